// Round 8
// baseline (791.955 us; speedup 1.0000x reference)
//
#include <hip/hip_runtime.h>

// snn_layer: out[b,u,t] = (sum_f in[b,f,t] * w[f,u] > 1.0f) ? 1.0f : 0.0f
// B=128 F=512 T=256 U=1024, fp32 in/out.
//
// fp32 has no MFMA on CDNA4 -> exact bf16 hi/lo split, 3-pass MFMA:
//   h ~= Ah*Bh + Ah*Bl + Al*Bh   (error ~1e-5; threshold band |h-1|<=1e-3
// recomputed in fp32 with the verified sequential-fmaf order -> flip-free).
//
// Round-8 (counter-driven):
//  * R7's reg-double-buffer was DEFEATED by the compiler (VGPR=100 proves
//    the two fragment sets were never kept live; loads sunk to uses ->
//    zero prefetch distance). NT stores amplified WRITE 131->165 MB.
//    Both reverted.
//  * Base = R2 (best measured, 327us). Single change: staging via
//    REGISTERS + ds_write instead of global_load_lds -- the schedule the
//    fp32 fallback proves out on this problem (66% VALUBusy):
//      commit regs->LDS; barrier; load chunk c+1 -> regs; compute c; barrier
//    Loads are issued before ~1300 cyc of compute and consumed by the
//    ds_writes at the TOP of the next iteration -> compiler cannot sink
//    them; the barrier's vmcnt drain is ~free because the loads landed
//    under the compute. R2's drain sat right after issue = full RTT/chunk.
//  * Identical LDS bytes as the GLL version (same permuted global source,
//    linear 16B/lane dest) -> proven swizzled reads + epilogue untouched.

#define BB 128
#define FF 512
#define TT 256
#define UU 1024

typedef float v4f __attribute__((ext_vector_type(4)));
typedef short v8s __attribute__((ext_vector_type(8)));
typedef unsigned short v8us __attribute__((ext_vector_type(8)));

__device__ __forceinline__ unsigned short bf16rn(float x) {
    unsigned u = __float_as_uint(x);
    u = u + 0x7FFFu + ((u >> 16) & 1u);   // round-to-nearest-even
    return (unsigned short)(u >> 16);
}
__device__ __forceinline__ float bf16tof(unsigned short h) {
    return __uint_as_float(((unsigned)h) << 16);
}

// ---------------------------------------------------------------------------
// Prepass: transpose + hi/lo split (unchanged, verified).
// Panels of 512(f) x 256(cols): z<128 -> X batch z (row stride TT);
// z in [128,132) -> W column-strip s=z-128 (row stride UU).
// Output row-major [col][f], f contiguous (512 bf16 = 1024 B rows).
// ---------------------------------------------------------------------------
__global__ __launch_bounds__(256)
void prepass_kernel(const float* __restrict__ in, const float* __restrict__ w,
                    unsigned short* __restrict__ xth, unsigned short* __restrict__ xtl,
                    unsigned short* __restrict__ wth, unsigned short* __restrict__ wtl) {
    __shared__ float Ls[64][65];

    const int z = blockIdx.z;
    const float* src;
    int srow;
    unsigned short *dh, *dl;
    if (z < BB) {
        src = in + (size_t)z * FF * TT;  srow = TT;
        dh = xth + (size_t)z * TT * FF;  dl = xtl + (size_t)z * TT * FF;
    } else {
        const int s = z - BB;
        src = w + s * 256;               srow = UU;
        dh = wth + (size_t)s * 256 * FF; dl = wtl + (size_t)s * 256 * FF;
    }
    const int f0 = blockIdx.y * 64;
    const int c0 = blockIdx.x * 64;
    const int tid = threadIdx.x;
    const int r  = tid >> 4;
    const int c4 = (tid & 15) * 4;

#pragma unroll
    for (int i = 0; i < 4; i++) {
        const float4 v = *(const float4*)&src[(size_t)(f0 + r + 16 * i) * srow + c0 + c4];
        Ls[r + 16 * i][c4 + 0] = v.x;
        Ls[r + 16 * i][c4 + 1] = v.y;
        Ls[r + 16 * i][c4 + 2] = v.z;
        Ls[r + 16 * i][c4 + 3] = v.w;
    }
    __syncthreads();

#pragma unroll
    for (int i = 0; i < 2; i++) {
        const int orow = 32 * i + (tid >> 3);
        const int fs   = (tid & 7) * 8;
        v8us hp, lp;
#pragma unroll
        for (int k = 0; k < 8; k++) {
            const float a = Ls[fs + k][orow];
            const unsigned short h = bf16rn(a);
            hp[k] = h;
            lp[k] = bf16rn(a - bf16tof(h));
        }
        const size_t o = (size_t)(c0 + orow) * FF + f0 + fs;
        *(v8us*)&dh[o] = hp;
        *(v8us*)&dl[o] = lp;
    }
}

// ---------------------------------------------------------------------------
// Main MFMA GEMM. 128x128 tile, BK=32, 4 waves (2x2 of 64x64).
// LDS: single buffer Ah|Al|Bh|Bl, each [128 rows][32 bf16] (8 KB) = 32 KB.
// Staging: per-thread int4 load from the k-segment-permuted global address
// (same as the proven GLL source), ds_write 16B/lane to the linear dest.
// ---------------------------------------------------------------------------
__device__ __forceinline__ void compute_chunk(const unsigned short* S, v4f acc[4][4],
                                              int wm, int wn, int lr, int ksel) {
    v8s ah[4], al[4], bh[4], bl[4];
#pragma unroll
    for (int i = 0; i < 4; i++) {
        const int ra = (wm + i * 16 + lr) * 32 + ksel;
        ah[i] = *(const v8s*)&S[ra];
        al[i] = *(const v8s*)&S[4096 + ra];
    }
#pragma unroll
    for (int j = 0; j < 4; j++) {
        const int rb = (wn + j * 16 + lr) * 32 + ksel;
        bh[j] = *(const v8s*)&S[8192 + rb];
        bl[j] = *(const v8s*)&S[12288 + rb];
    }
#pragma unroll
    for (int i = 0; i < 4; i++)
#pragma unroll
        for (int j = 0; j < 4; j++) {
            acc[i][j] = __builtin_amdgcn_mfma_f32_16x16x32_bf16(ah[i], bh[j], acc[i][j], 0, 0, 0);
            acc[i][j] = __builtin_amdgcn_mfma_f32_16x16x32_bf16(ah[i], bl[j], acc[i][j], 0, 0, 0);
            acc[i][j] = __builtin_amdgcn_mfma_f32_16x16x32_bf16(al[i], bh[j], acc[i][j], 0, 0, 0);
        }
}

__global__ __launch_bounds__(256, 2)
void snn_mfma_kernel(const unsigned short* __restrict__ wth,
                     const unsigned short* __restrict__ wtl,
                     const unsigned short* __restrict__ xth,
                     const unsigned short* __restrict__ xtl,
                     const float* __restrict__ in, const float* __restrict__ w,
                     float* __restrict__ out) {
    __shared__ unsigned short smem[4 * 128 * 32];  // Ah | Al | Bh | Bl, 32 KB

    // XCD-chunked, b-major swizzle (proven: FETCH 507->390 MB).
    const int h = blockIdx.x;
    const int l = ((h & 7) << 8) | (h >> 3);
    const int b  = l >> 4;
    const int u0 = ((l >> 1) & 7) * 128;
    const int t0 = (l & 1) * 128;

    const int tid = threadIdx.x;
    const int wv  = tid >> 6;        // wave 0..3
    const int ln  = tid & 63;
    const int lr  = ln & 15;         // fragment m/n index
    const int lq  = ln >> 4;         // fragment k-quad
    const int wm  = (wv & 1) * 64;   // wave tile origin (u)
    const int wn  = (wv >> 1) * 64;  // wave tile origin (t)

    // staging source for this wave; all sources have 1024-B rows
    const char* gbase;
    if      (wv == 0) gbase = (const char*)wth + (size_t)u0 * (FF * 2);
    else if (wv == 1) gbase = (const char*)wtl + (size_t)u0 * (FF * 2);
    else if (wv == 2) gbase = (const char*)xth + ((size_t)b * TT + t0) * (FF * 2);
    else              gbase = (const char*)xtl + ((size_t)b * TT + t0) * (FF * 2);
    const int lrow = ln >> 2;                               // row within 16-row slab
    const int lseg = (((ln & 3) ^ ((lrow >> 1) & 3)) * 16); // XOR-swizzled source seg

    char* lbase = (char*)&smem[wv * 4096];  // this wave's 8 KB tile (linear dest)

    v4f acc[4][4];
#pragma unroll
    for (int i = 0; i < 4; i++)
#pragma unroll
        for (int j = 0; j < 4; j++) {
            v4f zz = {0.0f, 0.0f, 0.0f, 0.0f};
            acc[i][j] = zz;
        }

    // read-side segment select: same involution as the staged source
    const int ksel = (lq ^ ((lr >> 1) & 3)) * 8;

    // --- register-staged single-buffer pipeline (fp32-fallback schedule) ---
    int4 stg[8];
#pragma unroll
    for (int s = 0; s < 8; s++)       // prologue: chunk 0 -> regs
        stg[s] = *(const int4*)(gbase + (size_t)(s * 16 + lrow) * (FF * 2) + lseg);

#pragma unroll 1
    for (int c = 0; c < 16; c++) {
        // commit staged chunk c to LDS (16B/lane, linear: byte ln*16 in slab)
#pragma unroll
        for (int s = 0; s < 8; s++)
            *(int4*)(lbase + s * 1024 + ln * 16) = stg[s];
        __syncthreads();              // chunk c visible to all waves

        // prefetch chunk c+1 into regs; latency rides under compute below,
        // and the regs are consumed by next iteration's ds_writes.
        if (c + 1 < 16) {
#pragma unroll
            for (int s = 0; s < 8; s++)
                stg[s] = *(const int4*)(gbase + (size_t)(s * 16 + lrow) * (FF * 2)
                                        + (c + 1) * 64 + lseg);
        }

        compute_chunk(smem, acc, wm, wn, lr, ksel);
        __syncthreads();              // all waves done reading chunk c
    }

    // Epilogue. C/D layout: col = lane&15, row = (lane>>4)*4+reg.
    const float* xb   = in  + (size_t)b * FF * TT;
    float* __restrict__ outb = out + (size_t)b * UU * TT;
#pragma unroll
    for (int i = 0; i < 4; i++) {
#pragma unroll
        for (int r = 0; r < 4; r++) {
            const int u = u0 + wm + i * 16 + lq * 4 + r;
#pragma unroll
            for (int j = 0; j < 4; j++) {
                const int t = t0 + wn + j * 16 + lr;
                float hh = acc[i][j][r];
                if (__builtin_expect(__builtin_fabsf(hh - 1.0f) <= 1e-3f, 0)) {
                    // exact fp32 recompute: identical sequential fmaf order
                    // (f ascending from 0) as the verified fp32 kernel.
                    float s2 = 0.0f;
                    const float* wp = w  + u;
                    const float* xp = xb + t;
#pragma unroll 16
                    for (int f = 0; f < FF; f++)
                        s2 = fmaf(wp[(size_t)f * UU], xp[(size_t)f * TT], s2);
                    hh = s2;
                }
                outb[(size_t)u * TT + t] = hh > 1.0f ? 1.0f : 0.0f;
            }
        }
    }
}

// ---------------------------------------------------------------------------
// Fallback: previous verified fp32 vector-FMA kernel (used if ws too small).
// ---------------------------------------------------------------------------
__global__ __launch_bounds__(256, 4)
void snn_gemm_kernel(const float* __restrict__ in, const float* __restrict__ w,
                     float* __restrict__ out) {
    __shared__ float As[16][128];
    __shared__ float Bs[16][128];

    const int b  = blockIdx.z;
    const int u0 = blockIdx.y * 128;
    const int t0 = blockIdx.x * 128;

    const float* __restrict__ inb  = in  + (size_t)b * FF * TT;
    float* __restrict__       outb = out + (size_t)b * UU * TT;

    const int tid = threadIdx.x;
    const int tx  = tid & 15;
    const int ty  = tid >> 4;

    const int k0 = tid >> 5;
    const int c0 = (tid & 31) * 4;
    const int k1 = k0 + 8;

    float acc[8][8];
#pragma unroll
    for (int i = 0; i < 8; i++)
#pragma unroll
        for (int j = 0; j < 8; j++) acc[i][j] = 0.0f;

    float4 a_r0 = *(const float4*)&w[(size_t)k0 * UU + u0 + c0];
    float4 a_r1 = *(const float4*)&w[(size_t)k1 * UU + u0 + c0];
    float4 b_r0 = *(const float4*)&inb[k0 * TT + t0 + c0];
    float4 b_r1 = *(const float4*)&inb[k1 * TT + t0 + c0];

    for (int f0 = 0; f0 < FF; f0 += 16) {
        *(float4*)&As[k0][c0] = a_r0;
        *(float4*)&As[k1][c0] = a_r1;
        *(float4*)&Bs[k0][c0] = b_r0;
        *(float4*)&Bs[k1][c0] = b_r1;
        __syncthreads();

        if (f0 + 16 < FF) {
            const int fn = f0 + 16;
            a_r0 = *(const float4*)&w[(size_t)(fn + k0) * UU + u0 + c0];
            a_r1 = *(const float4*)&w[(size_t)(fn + k1) * UU + u0 + c0];
            b_r0 = *(const float4*)&inb[(fn + k0) * TT + t0 + c0];
            b_r1 = *(const float4*)&inb[(fn + k1) * TT + t0 + c0];
        }

#pragma unroll
        for (int k = 0; k < 16; k++) {
            const float4 a0 = *(const float4*)&As[k][ty * 4];
            const float4 a1 = *(const float4*)&As[k][ty * 4 + 64];
            const float4 v0 = *(const float4*)&Bs[k][tx * 4];
            const float4 v1 = *(const float4*)&Bs[k][tx * 4 + 64];
            const float am[8] = {a0.x, a0.y, a0.z, a0.w, a1.x, a1.y, a1.z, a1.w};
            const float bn[8] = {v0.x, v0.y, v0.z, v0.w, v1.x, v1.y, v1.z, v1.w};
#pragma unroll
            for (int i = 0; i < 8; i++)
#pragma unroll
                for (int j = 0; j < 8; j++)
                    acc[i][j] = fmaf(am[i], bn[j], acc[i][j]);
        }
        __syncthreads();
    }

#pragma unroll
    for (int i = 0; i < 8; i++) {
        const int m = (i < 4) ? (ty * 4 + i) : (64 + ty * 4 + i - 4);
        float* __restrict__ orow = outb + (size_t)(u0 + m) * TT + t0;
        float4 o0, o1;
        o0.x = acc[i][0] > 1.0f ? 1.0f : 0.0f;
        o0.y = acc[i][1] > 1.0f ? 1.0f : 0.0f;
        o0.z = acc[i][2] > 1.0f ? 1.0f : 0.0f;
        o0.w = acc[i][3] > 1.0f ? 1.0f : 0.0f;
        o1.x = acc[i][4] > 1.0f ? 1.0f : 0.0f;
        o1.y = acc[i][5] > 1.0f ? 1.0f : 0.0f;
        o1.z = acc[i][6] > 1.0f ? 1.0f : 0.0f;
        o1.w = acc[i][7] > 1.0f ? 1.0f : 0.0f;
        *(float4*)&orow[tx * 4]      = o0;
        *(float4*)&orow[tx * 4 + 64] = o1;
    }
}

extern "C" void kernel_launch(void* const* d_in, const int* in_sizes, int n_in,
                              void* d_out, int out_size, void* d_ws, size_t ws_size,
                              hipStream_t stream) {
    const float* in = (const float*)d_in[0];  // [128,512,256]
    const float* w  = (const float*)d_in[1];  // [512,1024]
    float* out      = (float*)d_out;          // [128,1024,256]

    const size_t XN  = (size_t)BB * TT * FF;
    const size_t WN  = (size_t)UU * FF;
    const size_t NEED = (2 * XN + 2 * WN) * sizeof(unsigned short);

    if (ws_size >= NEED) {
        unsigned short* xth = (unsigned short*)d_ws;
        unsigned short* xtl = xth + XN;
        unsigned short* wth = xtl + XN;
        unsigned short* wtl = wth + WN;
        prepass_kernel<<<dim3(4, 8, 132), dim3(256), 0, stream>>>(in, w, xth, xtl, wth, wtl);
        snn_mfma_kernel<<<dim3(2048), dim3(256), 0, stream>>>(
            wth, wtl, xth, xtl, in, w, out);
    } else {
        snn_gemm_kernel<<<dim3(TT / 128, UU / 128, BB), dim3(256), 0, stream>>>(in, w, out);
    }
}

// Round 10
// 505.656 us; speedup vs baseline: 1.5662x; 1.5662x over previous
//
#include <hip/hip_runtime.h>

// snn_layer: out[b,u,t] = (sum_f in[b,f,t] * w[f,u] > 1.0f) ? 1.0f : 0.0f
// B=128 F=512 T=256 U=1024, fp32 in/out.
//
// fp32 has no MFMA on CDNA4 -> exact bf16 hi/lo split, 3-pass MFMA:
//   h ~= Ah*Bh + Ah*Bl + Al*Bh   (error ~1e-5; threshold band |h-1|<=1e-3
// recomputed in fp32 with the verified sequential-fmaf order -> flip-free).
//
// Round-10 = Round-9 with the compile fix: __builtin_nontemporal_store
// requires a clang ext_vector pointer, not HIP's float4 class type.
// Theory under test (from R2's counters): FETCH 390MB @ 1.19TB/s = 327us
// exactly -> fetch-bound, 4.7x over-fetch; excess ~300MB = W re-fetched
// per-b because the output write stream (~4MB per 64-block window)
// thrashes the 4MB XCD L2. Fix: full-line (128B) nontemporal output
// stores via a per-wave LDS bounce of the 64x64 output tile -> no write
// amplification (R7 failed with SCALAR NT = partial lines), output
// bypasses L2, W stays resident.

#define BB 128
#define FF 512
#define TT 256
#define UU 1024

typedef float v4f __attribute__((ext_vector_type(4)));
typedef short v8s __attribute__((ext_vector_type(8)));
typedef unsigned short v8us __attribute__((ext_vector_type(8)));

__device__ __forceinline__ unsigned short bf16rn(float x) {
    unsigned u = __float_as_uint(x);
    u = u + 0x7FFFu + ((u >> 16) & 1u);   // round-to-nearest-even
    return (unsigned short)(u >> 16);
}
__device__ __forceinline__ float bf16tof(unsigned short h) {
    return __uint_as_float(((unsigned)h) << 16);
}

// ---------------------------------------------------------------------------
// Prepass: transpose + hi/lo split (unchanged, verified).
// ---------------------------------------------------------------------------
__global__ __launch_bounds__(256)
void prepass_kernel(const float* __restrict__ in, const float* __restrict__ w,
                    unsigned short* __restrict__ xth, unsigned short* __restrict__ xtl,
                    unsigned short* __restrict__ wth, unsigned short* __restrict__ wtl) {
    __shared__ float Ls[64][65];

    const int z = blockIdx.z;
    const float* src;
    int srow;
    unsigned short *dh, *dl;
    if (z < BB) {
        src = in + (size_t)z * FF * TT;  srow = TT;
        dh = xth + (size_t)z * TT * FF;  dl = xtl + (size_t)z * TT * FF;
    } else {
        const int s = z - BB;
        src = w + s * 256;               srow = UU;
        dh = wth + (size_t)s * 256 * FF; dl = wtl + (size_t)s * 256 * FF;
    }
    const int f0 = blockIdx.y * 64;
    const int c0 = blockIdx.x * 64;
    const int tid = threadIdx.x;
    const int r  = tid >> 4;
    const int c4 = (tid & 15) * 4;

#pragma unroll
    for (int i = 0; i < 4; i++) {
        const float4 v = *(const float4*)&src[(size_t)(f0 + r + 16 * i) * srow + c0 + c4];
        Ls[r + 16 * i][c4 + 0] = v.x;
        Ls[r + 16 * i][c4 + 1] = v.y;
        Ls[r + 16 * i][c4 + 2] = v.z;
        Ls[r + 16 * i][c4 + 3] = v.w;
    }
    __syncthreads();

#pragma unroll
    for (int i = 0; i < 2; i++) {
        const int orow = 32 * i + (tid >> 3);
        const int fs   = (tid & 7) * 8;
        v8us hp, lp;
#pragma unroll
        for (int k = 0; k < 8; k++) {
            const float a = Ls[fs + k][orow];
            const unsigned short h = bf16rn(a);
            hp[k] = h;
            lp[k] = bf16rn(a - bf16tof(h));
        }
        const size_t o = (size_t)(c0 + orow) * FF + f0 + fs;
        *(v8us*)&dh[o] = hp;
        *(v8us*)&dl[o] = lp;
    }
}

// ---------------------------------------------------------------------------
// Main MFMA GEMM (R2 structure). 128x128 tile, BK=32, 4 waves (2x2 of 64x64).
// LDS: single buffer Ah|Al|Bh|Bl, each [128 rows][32 bf16] (8 KB) = 32 KB.
// global_load_lds staging; k-segments XOR-permuted at the global source,
// un-permuted at the fragment read (same involution).
// ---------------------------------------------------------------------------
#define GLL(g, l) __builtin_amdgcn_global_load_lds(                     \
    (const __attribute__((address_space(1))) void*)(g),                 \
    (__attribute__((address_space(3))) void*)(l), 16, 0, 0)

__device__ __forceinline__ void stage_chunk(const char* gbase, unsigned short* lbase,
                                            int fbyte, int lrow, int lseg) {
#pragma unroll
    for (int s = 0; s < 8; s++) {
        const char* ga = gbase + (size_t)(s * 16 + lrow) * (FF * 2) + fbyte + lseg;
        GLL(ga, (char*)lbase + s * 1024);
    }
}

__device__ __forceinline__ void compute_chunk(const unsigned short* S, v4f acc[4][4],
                                              int wm, int wn, int lr, int ksel) {
    v8s ah[4], al[4], bh[4], bl[4];
#pragma unroll
    for (int i = 0; i < 4; i++) {
        const int ra = (wm + i * 16 + lr) * 32 + ksel;
        ah[i] = *(const v8s*)&S[ra];
        al[i] = *(const v8s*)&S[4096 + ra];
    }
#pragma unroll
    for (int j = 0; j < 4; j++) {
        const int rb = (wn + j * 16 + lr) * 32 + ksel;
        bh[j] = *(const v8s*)&S[8192 + rb];
        bl[j] = *(const v8s*)&S[12288 + rb];
    }
#pragma unroll
    for (int i = 0; i < 4; i++)
#pragma unroll
        for (int j = 0; j < 4; j++) {
            acc[i][j] = __builtin_amdgcn_mfma_f32_16x16x32_bf16(ah[i], bh[j], acc[i][j], 0, 0, 0);
            acc[i][j] = __builtin_amdgcn_mfma_f32_16x16x32_bf16(ah[i], bl[j], acc[i][j], 0, 0, 0);
            acc[i][j] = __builtin_amdgcn_mfma_f32_16x16x32_bf16(al[i], bh[j], acc[i][j], 0, 0, 0);
        }
}

__global__ __launch_bounds__(256, 3)
void snn_mfma_kernel(const unsigned short* __restrict__ wth,
                     const unsigned short* __restrict__ wtl,
                     const unsigned short* __restrict__ xth,
                     const unsigned short* __restrict__ xtl,
                     const float* __restrict__ in, const float* __restrict__ w,
                     float* __restrict__ out) {
    __shared__ unsigned short smem[4 * 128 * 32];  // Ah | Al | Bh | Bl, 32 KB

    // XCD-chunked, b-major swizzle (proven: FETCH 507->390 MB).
    const int h = blockIdx.x;
    const int l = ((h & 7) << 8) | (h >> 3);
    const int b  = l >> 4;
    const int u0 = ((l >> 1) & 7) * 128;
    const int t0 = (l & 1) * 128;

    const int tid = threadIdx.x;
    const int wv  = tid >> 6;        // wave 0..3
    const int ln  = tid & 63;
    const int lr  = ln & 15;         // fragment m/n index
    const int lq  = ln >> 4;         // fragment k-quad
    const int wm  = (wv & 1) * 64;   // wave tile origin (u)
    const int wn  = (wv >> 1) * 64;  // wave tile origin (t)

    // staging source for this wave; all sources have 1024-B rows
    const char* gbase;
    if      (wv == 0) gbase = (const char*)wth + (size_t)u0 * (FF * 2);
    else if (wv == 1) gbase = (const char*)wtl + (size_t)u0 * (FF * 2);
    else if (wv == 2) gbase = (const char*)xth + ((size_t)b * TT + t0) * (FF * 2);
    else              gbase = (const char*)xtl + ((size_t)b * TT + t0) * (FF * 2);
    const int lrow = ln >> 2;                               // row within 16-row slab
    const int lseg = (((ln & 3) ^ ((lrow >> 1) & 3)) * 16); // XOR-swizzled source seg

    unsigned short* lbase = &smem[wv * 4096];  // this wave's 8 KB stage tile

    v4f acc[4][4];
#pragma unroll
    for (int i = 0; i < 4; i++)
#pragma unroll
        for (int j = 0; j < 4; j++) {
            v4f zz = {0.0f, 0.0f, 0.0f, 0.0f};
            acc[i][j] = zz;
        }

    // read-side segment select: same involution as the staged source
    const int ksel = (lq ^ ((lr >> 1) & 3)) * 8;

    for (int f0 = 0; f0 < FF; f0 += 32) {
        stage_chunk(gbase, lbase, f0 * 2, lrow, lseg);
        __syncthreads();
        compute_chunk(smem, acc, wm, wn, lr, ksel);
        __syncthreads();
    }

    // ---- Epilogue: band-fix -> per-wave LDS transpose -> full-line NT ----
    const float* xb   = in  + (size_t)b * FF * TT;
    float* __restrict__ outb = out + (size_t)b * UU * TT;
    float* Rf = (float*)((char*)smem + wv * 8192);   // wave's 8 KB = 64x32 f32

#pragma unroll
    for (int jh = 0; jh < 2; jh++) {
        // write 0/1 values for j-pair {2jh, 2jh+1} into [64u][32t] region
#pragma unroll
        for (int i = 0; i < 4; i++) {
#pragma unroll
            for (int jj = 0; jj < 2; jj++) {
                const int j = jh * 2 + jj;
#pragma unroll
                for (int r = 0; r < 4; r++) {
                    float hh = acc[i][j][r];
                    if (__builtin_expect(__builtin_fabsf(hh - 1.0f) <= 1e-3f, 0)) {
                        // exact fp32 recompute: identical sequential fmaf
                        // order (f ascending) as the verified fp32 kernel.
                        const int u = u0 + wm + i * 16 + lq * 4 + r;
                        const int t = t0 + wn + j * 16 + lr;
                        float s2 = 0.0f;
                        const float* wp = w  + u;
                        const float* xp = xb + t;
#pragma unroll 16
                        for (int f = 0; f < FF; f++)
                            s2 = fmaf(wp[(size_t)f * UU], xp[(size_t)f * TT], s2);
                        hh = s2;
                    }
                    Rf[(i * 16 + lq * 4 + r) * 32 + jj * 16 + lr] =
                        hh > 1.0f ? 1.0f : 0.0f;
                }
            }
        }
        __syncthreads();   // uniform across waves; orders ds_write->ds_read

        // linear v4f readback (1024 contiguous B per 8-lane group ->
        // conflict-free) + nontemporal full-line stores (8 lanes = 128 B).
#pragma unroll
        for (int rr = 0; rr < 8; rr++) {
            const int row = rr * 8 + (ln >> 3);
            const int c4  = (ln & 7) * 4;
            const v4f v = *(const v4f*)&Rf[row * 32 + c4];
            __builtin_nontemporal_store(v,
                (v4f*)&outb[(size_t)(u0 + wm + row) * TT + t0 + wn + jh * 32 + c4]);
        }
        __syncthreads();   // region reused by next half
    }
}

// ---------------------------------------------------------------------------
// Fallback: previous verified fp32 vector-FMA kernel (used if ws too small).
// ---------------------------------------------------------------------------
__global__ __launch_bounds__(256, 4)
void snn_gemm_kernel(const float* __restrict__ in, const float* __restrict__ w,
                     float* __restrict__ out) {
    __shared__ float As[16][128];
    __shared__ float Bs[16][128];

    const int b  = blockIdx.z;
    const int u0 = blockIdx.y * 128;
    const int t0 = blockIdx.x * 128;

    const float* __restrict__ inb  = in  + (size_t)b * FF * TT;
    float* __restrict__       outb = out + (size_t)b * UU * TT;

    const int tid = threadIdx.x;
    const int tx  = tid & 15;
    const int ty  = tid >> 4;

    const int k0 = tid >> 5;
    const int c0 = (tid & 31) * 4;
    const int k1 = k0 + 8;

    float acc[8][8];
#pragma unroll
    for (int i = 0; i < 8; i++)
#pragma unroll
        for (int j = 0; j < 8; j++) acc[i][j] = 0.0f;

    float4 a_r0 = *(const float4*)&w[(size_t)k0 * UU + u0 + c0];
    float4 a_r1 = *(const float4*)&w[(size_t)k1 * UU + u0 + c0];
    float4 b_r0 = *(const float4*)&inb[k0 * TT + t0 + c0];
    float4 b_r1 = *(const float4*)&inb[k1 * TT + t0 + c0];

    for (int f0 = 0; f0 < FF; f0 += 16) {
        *(float4*)&As[k0][c0] = a_r0;
        *(float4*)&As[k1][c0] = a_r1;
        *(float4*)&Bs[k0][c0] = b_r0;
        *(float4*)&Bs[k1][c0] = b_r1;
        __syncthreads();

        if (f0 + 16 < FF) {
            const int fn = f0 + 16;
            a_r0 = *(const float4*)&w[(size_t)(fn + k0) * UU + u0 + c0];
            a_r1 = *(const float4*)&w[(size_t)(fn + k1) * UU + u0 + c0];
            b_r0 = *(const float4*)&inb[(fn + k0) * TT + t0 + c0];
            b_r1 = *(const float4*)&inb[(fn + k1) * TT + t0 + c0];
        }

#pragma unroll
        for (int k = 0; k < 16; k++) {
            const float4 a0 = *(const float4*)&As[k][ty * 4];
            const float4 a1 = *(const float4*)&As[k][ty * 4 + 64];
            const float4 v0 = *(const float4*)&Bs[k][tx * 4];
            const float4 v1 = *(const float4*)&Bs[k][tx * 4 + 64];
            const float am[8] = {a0.x, a0.y, a0.z, a0.w, a1.x, a1.y, a1.z, a1.w};
            const float bn[8] = {v0.x, v0.y, v0.z, v0.w, v1.x, v1.y, v1.z, v1.w};
#pragma unroll
            for (int i = 0; i < 8; i++)
#pragma unroll
                for (int j = 0; j < 8; j++)
                    acc[i][j] = fmaf(am[i], bn[j], acc[i][j]);
        }
        __syncthreads();
    }

#pragma unroll
    for (int i = 0; i < 8; i++) {
        const int m = (i < 4) ? (ty * 4 + i) : (64 + ty * 4 + i - 4);
        float* __restrict__ orow = outb + (size_t)(u0 + m) * TT + t0;
        float4 o0, o1;
        o0.x = acc[i][0] > 1.0f ? 1.0f : 0.0f;
        o0.y = acc[i][1] > 1.0f ? 1.0f : 0.0f;
        o0.z = acc[i][2] > 1.0f ? 1.0f : 0.0f;
        o0.w = acc[i][3] > 1.0f ? 1.0f : 0.0f;
        o1.x = acc[i][4] > 1.0f ? 1.0f : 0.0f;
        o1.y = acc[i][5] > 1.0f ? 1.0f : 0.0f;
        o1.z = acc[i][6] > 1.0f ? 1.0f : 0.0f;
        o1.w = acc[i][7] > 1.0f ? 1.0f : 0.0f;
        *(float4*)&orow[tx * 4]      = o0;
        *(float4*)&orow[tx * 4 + 64] = o1;
    }
}

extern "C" void kernel_launch(void* const* d_in, const int* in_sizes, int n_in,
                              void* d_out, int out_size, void* d_ws, size_t ws_size,
                              hipStream_t stream) {
    const float* in = (const float*)d_in[0];  // [128,512,256]
    const float* w  = (const float*)d_in[1];  // [512,1024]
    float* out      = (float*)d_out;          // [128,1024,256]

    const size_t XN  = (size_t)BB * TT * FF;
    const size_t WN  = (size_t)UU * FF;
    const size_t NEED = (2 * XN + 2 * WN) * sizeof(unsigned short);

    if (ws_size >= NEED) {
        unsigned short* xth = (unsigned short*)d_ws;
        unsigned short* xtl = xth + XN;
        unsigned short* wth = xtl + XN;
        unsigned short* wtl = wth + WN;
        prepass_kernel<<<dim3(4, 8, 132), dim3(256), 0, stream>>>(in, w, xth, xtl, wth, wtl);
        snn_mfma_kernel<<<dim3(2048), dim3(256), 0, stream>>>(
            wth, wtl, xth, xtl, in, w, out);
    } else {
        snn_gemm_kernel<<<dim3(TT / 128, UU / 128, BB), dim3(256), 0, stream>>>(in, w, out);
    }
}